// Round 2
// baseline (451.350 us; speedup 1.0000x reference)
//
#include <hip/hip_runtime.h>
#include <math.h>

#define NHID 128

typedef __bf16 bf16x8 __attribute__((ext_vector_type(8)));
typedef float f32x4 __attribute__((ext_vector_type(4)));

// pack two fp32 -> two bf16 (round-to-nearest, ties away): 3 VALU ops
__device__ __forceinline__ unsigned int pack_bf16_rn(float f0, float f1) {
  unsigned int u0 = __float_as_uint(f0) + 0x8000u;
  unsigned int u1 = __float_as_uint(f1) + 0x8000u;
  // result = (hi16(u1)<<16) | hi16(u0)  via v_perm_b32
  return __builtin_amdgcn_perm(u1, u0, 0x07060302u);
}

union frag_u { unsigned int u[4]; bf16x8 v; };

__global__ __launch_bounds__(512, 4)
void mlp_edge_decoder(const float* __restrict__ inputs,
                      const int* __restrict__ x_idx,
                      const int* __restrict__ y_idx,
                      const float* __restrict__ W1,
                      const float* __restrict__ bias1,
                      const float* __restrict__ W2,
                      const float* __restrict__ bias2,
                      float* __restrict__ out,
                      int n_edges)
{
  // W1 pre-swizzled into MFMA B-fragment-major order:
  // sB[ks][nt][lane] = 16B frag: j=0..7 -> W1[k=ks*32+(lane>>4)*8+j][n=nt*16+(lane&15)]
  // 8*8*64*16B = 64 KB exactly -> 2 blocks/CU
  __shared__ __align__(16) unsigned short sB[8 * 8 * 64 * 8];

  const int tid = threadIdx.x;

  // ---- one-time stage: coalesced float4 reads of W1, scattered b16 LDS writes ----
  for (int i = tid; i < 256 * NHID / 4; i += 512) {
    float4 w = ((const float4*)W1)[i];
    int base = i * 4;
    int k  = base >> 7;         // W1 row-major [k][n], float4 spans 4 n's of one k
    int n0 = base & 127;
    int ks = k >> 5, q = (k >> 3) & 3, j = k & 7;
    #pragma unroll
    for (int c = 0; c < 4; ++c) {
      int n = n0 + c;
      int nt = n >> 4, m = n & 15;
      int lane = q * 16 + m;
      unsigned int u = __float_as_uint((&w.x)[c]) + 0x8000u;
      sB[(((ks * 8 + nt) * 64) + lane) * 8 + j] = (unsigned short)(u >> 16);
    }
  }
  __syncthreads();   // the ONLY barrier; everything after is wave-independent

  const int lane = tid & 63;
  const int wv   = tid >> 6;
  const int m15  = lane & 15;
  const int q    = lane >> 4;

  // per-lane epilogue constants: cols n = nt*16 + m15
  float b1v[8], w2v[8];
  #pragma unroll
  for (int nt = 0; nt < 8; ++nt) {
    b1v[nt] = bias1[nt * 16 + m15];
    w2v[nt] = W2[nt * 16 + m15];
  }
  const float b2 = bias2[0];

  const int gwave   = blockIdx.x * 8 + wv;
  const int nwaves  = gridDim.x * 8;
  const int nstrips = (n_edges + 31) >> 5;   // strips of 32 edges (2 x 16-row sub-strips)

  const bf16x8* __restrict__ bfrags = (const bf16x8*)sB;

  for (int strip = gwave; strip < nstrips; strip += nwaves) {
    const int e0 = strip * 32;

    // node-row base pointers; A-frag: row = m15, k-bytes = ks*128 + q*32
    const float* ax[2];
    const float* ay[2];
    #pragma unroll
    for (int s = 0; s < 2; ++s) {
      int e  = e0 + s * 16 + m15;
      int ec = (e < n_edges) ? e : (n_edges - 1);
      ax[s] = inputs + (size_t)x_idx[ec] * NHID;
      ay[s] = inputs + (size_t)y_idx[ec] * NHID;
    }

    f32x4 acc[2][8];
    #pragma unroll
    for (int s = 0; s < 2; ++s)
      #pragma unroll
      for (int nt = 0; nt < 8; ++nt)
        acc[s][nt] = (f32x4){0.f, 0.f, 0.f, 0.f};

    // prefetch raw A for ks=0
    float4 r0[2], r1[2];
    #pragma unroll
    for (int s = 0; s < 2; ++s) {
      r0[s] = *(const float4*)(ax[s] + q * 8);
      r1[s] = *(const float4*)(ax[s] + q * 8 + 4);
    }

    #pragma unroll
    for (int ks = 0; ks < 8; ++ks) {
      // convert current raw fp32 -> bf16 A-frags
      bf16x8 af[2];
      #pragma unroll
      for (int s = 0; s < 2; ++s) {
        frag_u cv;
        cv.u[0] = pack_bf16_rn(r0[s].x, r0[s].y);
        cv.u[1] = pack_bf16_rn(r0[s].z, r0[s].w);
        cv.u[2] = pack_bf16_rn(r1[s].x, r1[s].y);
        cv.u[3] = pack_bf16_rn(r1[s].z, r1[s].w);
        af[s] = cv.v;
      }
      // prefetch next ks (x-node for k<128, y-node for k>=128)
      if (ks < 7) {
        const int kn  = ks + 1;
        const int off = (kn & 3) * 32 + q * 8;
        #pragma unroll
        for (int s = 0; s < 2; ++s) {
          const float* p = (kn < 4) ? ax[s] : ay[s];
          r0[s] = *(const float4*)(p + off);
          r1[s] = *(const float4*)(p + off + 4);
        }
      }
      // 16 MFMAs: 8 B-frag reads, each feeding both sub-strips
      const bf16x8* bp = bfrags + (ks * 8) * 64 + lane;
      #pragma unroll
      for (int nt = 0; nt < 8; ++nt) {
        bf16x8 bf = bp[nt * 64];   // stride-1 ds_read_b128, conflict-free
        acc[0][nt] = __builtin_amdgcn_mfma_f32_16x16x32_bf16(af[0], bf, acc[0][nt], 0, 0, 0);
        acc[1][nt] = __builtin_amdgcn_mfma_f32_16x16x32_bf16(af[1], bf, acc[1][nt], 0, 0, 0);
      }
    }

    // ---- epilogue, fully in-register ----
    // D layout: col = lane&15 (= n within nt tile), row = q*4 + r
    #pragma unroll
    for (int s = 0; s < 2; ++s) {
      float4 sv;
      #pragma unroll
      for (int r = 0; r < 4; ++r) {
        float t = 0.f;
        #pragma unroll
        for (int nt = 0; nt < 8; ++nt) {
          float h = acc[s][nt][r] + b1v[nt];
          h = fmaxf(h, 0.f);
          t = fmaf(h, w2v[nt], t);
        }
        t += __shfl_xor(t, 1);
        t += __shfl_xor(t, 2);
        t += __shfl_xor(t, 4);
        t += __shfl_xor(t, 8);
        (&sv.x)[r] = t;
      }
      if (m15 == 0) {
        int e = e0 + s * 16 + q * 4;   // multiple of 4 -> 16B aligned
        float4 ov;
        #pragma unroll
        for (int r = 0; r < 4; ++r)
          (&ov.x)[r] = 1.f / (1.f + __expf(-((&sv.x)[r] + b2)));
        if (e + 3 < n_edges) {
          *(float4*)(out + e) = ov;
        } else {
          #pragma unroll
          for (int r = 0; r < 4; ++r)
            if (e + r < n_edges) out[e + r] = (&ov.x)[r];
        }
      }
    }
  }
}

extern "C" void kernel_launch(void* const* d_in, const int* in_sizes, int n_in,
                              void* d_out, int out_size, void* d_ws, size_t ws_size,
                              hipStream_t stream) {
  const float* inputs = (const float*)d_in[0];
  const int*   x_idx  = (const int*)d_in[1];
  const int*   y_idx  = (const int*)d_in[2];
  const float* W1     = (const float*)d_in[3];
  const float* bias1  = (const float*)d_in[4];
  const float* W2     = (const float*)d_in[5];
  const float* bias2  = (const float*)d_in[6];
  float* out = (float*)d_out;
  const int n_edges = in_sizes[1];

  // 512 blocks x 512 threads: 2 blocks/CU (64KB LDS), target 16 waves/CU
  hipLaunchKernelGGL(mlp_edge_decoder, dim3(512), dim3(512), 0, stream,
                     inputs, x_idx, y_idx, W1, bias1, W2, bias2, out, n_edges);
}